// Round 10
// baseline (143.970 us; speedup 1.0000x reference)
//
#include <hip/hip_runtime.h>
#include <hip/hip_bf16.h>

typedef short short8 __attribute__((ext_vector_type(8)));
typedef float f32x4 __attribute__((ext_vector_type(4)));

constexpr int N_  = 32;
constexpr int C_  = 256;
constexpr int K_  = 256;
constexpr int H_  = 56;
constexpr int W_  = 56;
constexpr int HW_ = H_ * W_;             // 3136
constexpr int NW_ = K_ * C_ * 9;         // 589824

constexpr int TH   = 4;                  // output rows per band (128B-aligned writes)
constexpr int NB   = 14;                 // bands
constexpr int HR   = 6, HC = 58;         // halo rows/cols
constexpr int NH   = HR * HC;            // 348 halo positions
constexpr int BROW = 80;                 // B LDS row stride (32c bf16 = 64B + 16 pad)
constexpr int BSZ  = NH * BROW;          // 27840 per buffer
constexpr int LDSB = 4 * BSZ;            // 111360: 4-buffer ring
constexpr int NPAIR2 = 8 * NH;           // 2784 (c-quad, hidx) staging elems
constexpr int SITER  = 6;                // ceil(2784/512)
constexpr int ASTEP  = 16384;            // one step-tile: 256k x 32c bf16

constexpr int NQB   = 1152;              // quant blocks (589824 / 512, exact)
constexpr int WS_P1 = 4;                 // 256 abs partials
constexpr int WS_P2 = 300;               // 1152 masked-sum partials
constexpr int WS_P3 = 1500;              // 1152 masked-cnt partials
constexpr size_t WS_WQ = 16384;
constexpr size_t WS_NEEDED = WS_WQ + (size_t)NW_ * 2;

__device__ __forceinline__ unsigned f2bf(float f) {  // RNE fp32->bf16 bits
    unsigned u = __builtin_bit_cast(unsigned, f);
    return (u + 0x7FFFu + ((u >> 16) & 1u)) >> 16;
}

// ---------------- reductions (deterministic, no atomics) ----------------
__global__ void k_abs_partial(const float* __restrict__ w, float* __restrict__ ws) {
    __shared__ float sm[4];
    float s = 0.f;
    for (int i = blockIdx.x * 256 + threadIdx.x; i < NW_; i += 256 * 256)
        s += fabsf(w[i]);
    #pragma unroll
    for (int o = 32; o > 0; o >>= 1) s += __shfl_down(s, o, 64);
    const int wid = threadIdx.x >> 6, lane = threadIdx.x & 63;
    if (lane == 0) sm[wid] = s;
    __syncthreads();
    if (threadIdx.x == 0) {
        float r = 0.f;
        for (int i = 0; i < 4; ++i) r += sm[i];
        ws[WS_P1 + blockIdx.x] = r;
    }
}

__device__ __forceinline__ float reduce256_all(const float* __restrict__ p, float* sm) {
    float v = threadIdx.x < 256 ? p[threadIdx.x] : 0.f;
    #pragma unroll
    for (int o = 32; o > 0; o >>= 1) v += __shfl_down(v, o, 64);
    const int wid = threadIdx.x >> 6, lane = threadIdx.x & 63;
    __syncthreads();
    if (lane == 0) sm[wid] = v;
    __syncthreads();
    float total = 0.f;
    #pragma unroll
    for (int i = 0; i < 8; ++i) total += sm[i];
    return total;
}

// quantize signs to bf16 {+1,-1,0} in [step=(chi*9+rs)][k][c5] layout AND write
// per-block masked partials (sum,cnt) -> P2/P3. Grid = 1152 x 512 (exact cover).
__global__ __launch_bounds__(512) void k_quant(const float* __restrict__ w,
                                               float* __restrict__ ws,
                                               unsigned short* __restrict__ wq) {
    __shared__ float sm[8];
    const float total = reduce256_all(ws + WS_P1, sm);
    const float thr = 0.75f * total / (float)NW_;
    const int i = blockIdx.x * 512 + threadIdx.x;
    const float v = w[i];
    const unsigned short q = v > thr ? (unsigned short)0x3F80
                                     : (v < -thr ? (unsigned short)0xBF80 : (unsigned short)0);
    const int k   = i / 2304;
    const int rem = i - k * 2304;
    const int c   = rem / 9;
    const int rs  = rem - c * 9;
    const int chi = c >> 5, c5 = c & 31;
    wq[(size_t)(chi * 9 + rs) * 8192 + (k << 5) + c5] = q;
    // masked partials for alpha
    const float a = fabsf(v);
    float s = a > thr ? a : 0.f;
    float cn = a > thr ? 1.f : 0.f;
    #pragma unroll
    for (int o = 32; o > 0; o >>= 1) { s += __shfl_down(s, o, 64); cn += __shfl_down(cn, o, 64); }
    __shared__ float sm2[16];
    const int wid = threadIdx.x >> 6, lane = threadIdx.x & 63;
    __syncthreads();
    if (lane == 0) { sm2[wid] = s; sm2[8 + wid] = cn; }
    __syncthreads();
    if (threadIdx.x == 0) {
        float S = 0.f, C2 = 0.f;
        for (int j = 0; j < 8; ++j) { S += sm2[j]; C2 += sm2[8 + j]; }
        ws[WS_P2 + blockIdx.x] = S;
        ws[WS_P3 + blockIdx.x] = C2;
    }
}

// ---------------- fallback-path helper kernels (tiny ws only) ----------------
__global__ void k_fb_total(float* __restrict__ ws) {
    __shared__ float sm[4];
    float v = ws[WS_P1 + threadIdx.x];
    #pragma unroll
    for (int o = 32; o > 0; o >>= 1) v += __shfl_down(v, o, 64);
    const int wid = threadIdx.x >> 6, lane = threadIdx.x & 63;
    if (lane == 0) sm[wid] = v;
    __syncthreads();
    if (threadIdx.x == 0) {
        float r = 0.f;
        for (int i = 0; i < 4; ++i) r += sm[i];
        ws[0] = r;
    }
}

__global__ void k_fb_masked(const float* __restrict__ w, float* __restrict__ ws) {
    const float thr = 0.75f * ws[0] / (float)NW_;
    float s = 0.f, c = 0.f;
    for (int i = blockIdx.x * 256 + threadIdx.x; i < NW_; i += 256 * 256) {
        float a = fabsf(w[i]);
        if (a > thr) { s += a; c += 1.f; }
    }
    #pragma unroll
    for (int o = 32; o > 0; o >>= 1) { s += __shfl_down(s, o, 64); c += __shfl_down(c, o, 64); }
    __shared__ float sm[8];
    const int wid = threadIdx.x >> 6, lane = threadIdx.x & 63;
    if (lane == 0) { sm[wid] = s; sm[4 + wid] = c; }
    __syncthreads();
    if (threadIdx.x == 0) {
        float S = 0.f, C2 = 0.f;
        for (int i = 0; i < 4; ++i) { S += sm[i]; C2 += sm[i + 4]; }
        ws[WS_P2 + blockIdx.x] = S;
        ws[WS_P3 + blockIdx.x] = C2;
    }
}

__global__ void k_final_masked(float* __restrict__ ws) {
    __shared__ float sm[8];
    float s = ws[WS_P2 + threadIdx.x];
    float c = ws[WS_P3 + threadIdx.x];
    #pragma unroll
    for (int o = 32; o > 0; o >>= 1) { s += __shfl_down(s, o, 64); c += __shfl_down(c, o, 64); }
    const int wid = threadIdx.x >> 6, lane = threadIdx.x & 63;
    if (lane == 0) { sm[wid] = s; sm[4 + wid] = c; }
    __syncthreads();
    if (threadIdx.x == 0) {
        float S = 0.f, C2 = 0.f;
        for (int i = 0; i < 4; ++i) { S += sm[i]; C2 += sm[i + 4]; }
        ws[1] = S; ws[2] = C2;
    }
}

// ---------------- MFMA conv: R4 structure + 4-buffer LDS ring (half the barriers) ----
// Block: 256k x 224pos (4 rows x 56 cols), 8 waves = 4(k) x 2(pos).
// Wave: 64k x 112pos (4x7 frags, 28 MFMA / 4 A-glb / 7 B-lds reads per 32-ch step).
// A: direct global->reg from L2-resident wq, depth-1 parity pipeline.
// B: 4-buffer LDS ring. Chunk c reads buf[c&3], stages chunk c+2 into buf[(c+2)&3]
//    (issue rs==6, write rs==8); s_barrier only after ODD chunks (4 barriers total).
//    Hazard: writer of buf[(c+2)&3] vs its last reader (chunk c-2) is separated by
//    the pair barrier; reader of buf[c&3] vs its writer (chunk c-2) likewise.
constexpr int RSO_[9] = {
    (0*HC+0)*BROW, (0*HC+1)*BROW, (0*HC+2)*BROW,
    (1*HC+0)*BROW, (1*HC+1)*BROW, (1*HC+2)*BROW,
    (2*HC+0)*BROW, (2*HC+1)*BROW, (2*HC+2)*BROW };

struct ConvState {
    const float* xn;
    const char*  wqc;
    char*        ldsp;
    size_t       aoff;         // per-lane byte offset within a step tile
    int          tid;
    int          bB[7];        // per-lane B frag byte offsets within a buffer
    int          xrel[SITER];  // precomputed x offsets for halo staging
    unsigned     okm;          // validity bitmask for staging iters
};

__device__ __forceinline__ void load_a(short8 (&d)[4], const ConvState& st, int step) {
    const char* ap = st.wqc + (size_t)step * ASTEP + st.aoff;
    d[0] = *(const short8*)(ap);
    d[1] = *(const short8*)(ap + 1024);
    d[2] = *(const short8*)(ap + 2048);
    d[3] = *(const short8*)(ap + 3072);
}

__device__ __forceinline__ void issue_b(const ConvState& st, int c0, float (&bs)[SITER][4]) {
    #pragma unroll
    for (int it = 0; it < SITER; ++it) {
        const float* p = st.xn + (size_t)c0 * HW_ + st.xrel[it];
        bs[it][0] = p[0];
        bs[it][1] = p[HW_];
        bs[it][2] = p[2 * HW_];
        bs[it][3] = p[3 * HW_];
    }
}

__device__ __forceinline__ void write_b(const ConvState& st, int base,
                                        const float (&bs)[SITER][4]) {
    #pragma unroll
    for (int it = 0; it < SITER; ++it) {
        const int u = it * 512 + st.tid;
        if (u < NPAIR2) {
            const int c4 = u / NH, hidx = u - c4 * NH;
            const bool ok = (st.okm >> it) & 1u;
            const float f0 = ok ? bs[it][0] : 0.f;
            const float f1 = ok ? bs[it][1] : 0.f;
            const float f2 = ok ? bs[it][2] : 0.f;
            const float f3 = ok ? bs[it][3] : 0.f;
            uint2 v;
            v.x = f2bf(f0) | (f2bf(f1) << 16);
            v.y = f2bf(f2) | (f2bf(f3) << 16);
            *(uint2*)(st.ldsp + base + hidx * BROW + c4 * 8) = v;
        }
    }
}

template <int BUF, bool STAGE, bool BAR>
__device__ __forceinline__ void do_chunk(int chi, const ConvState& st,
                                         short8 (&afr)[2][4], f32x4 (&acc)[4][7],
                                         float (&bs)[SITER][4]) {
    constexpr int PAR    = BUF & 1;
    constexpr int rdbase = BUF * BSZ;
    constexpr int wrbase = ((BUF + 2) & 3) * BSZ;
    constexpr bool LASTCH = (BUF == 3) && !STAGE && !BAR;  // chunk 7
    #pragma unroll
    for (int rs = 0; rs < 9; ++rs) {
        const int cur = (PAR + rs) & 1, nxt = cur ^ 1;
        const int step = chi * 9 + rs;
        if (!(LASTCH && rs == 8))
            load_a(afr[nxt], st, step + 1);   // next step's A into the other reg set

        short8 bfr[7];
        #pragma unroll
        for (int nf = 0; nf < 7; ++nf)
            bfr[nf] = *(const short8*)(st.ldsp + rdbase + st.bB[nf] + RSO_[rs]);

        if (STAGE && rs == 6)
            issue_b(st, (chi + 2) * 32, bs);   // chunk c+2's x, 2 steps of hiding

        __builtin_amdgcn_s_setprio(1);
        #pragma unroll
        for (int nf = 0; nf < 7; ++nf)
            #pragma unroll
            for (int mf = 0; mf < 4; ++mf)
                acc[mf][nf] = __builtin_amdgcn_mfma_f32_16x16x32_bf16(
                    afr[cur][mf], bfr[nf], acc[mf][nf], 0, 0, 0);
        __builtin_amdgcn_s_setprio(0);

        if (rs == 8) {
            if (STAGE) write_b(st, wrbase, bs);
            if (BAR) {
                asm volatile("s_waitcnt lgkmcnt(0)" ::: "memory");
                __builtin_amdgcn_s_barrier();
            }
        }
    }
}

__global__ __launch_bounds__(512, 2) void conv_mfma(const float* __restrict__ x,
                                                    const unsigned short* __restrict__ wq,
                                                    const float* __restrict__ wsc,
                                                    float* __restrict__ out) {
    extern __shared__ char lds[];
    const int tid = threadIdx.x, lane = tid & 63, wid = tid >> 6;
    const int wm = wid & 3, wn = wid >> 2, lr = lane & 15, lg = lane >> 4;
    const int band = blockIdx.x, n = blockIdx.y;
    const int h0 = band * TH;

    ConvState st;
    st.xn   = x + (size_t)n * C_ * HW_;
    st.wqc  = (const char*)wq;
    st.ldsp = lds;
    st.aoff = (size_t)(wm * 64 + lr) * 64 + lg * 16;
    st.tid  = tid;
    #pragma unroll
    for (int nf = 0; nf < 7; ++nf) {
        const int pos = wn * 112 + nf * 16 + lr;
        const int y = pos / 56, xx = pos - y * 56;
        st.bB[nf] = (y * HC + xx) * BROW + lg * 16;
    }
    // precompute halo staging offsets + validity
    st.okm = 0;
    #pragma unroll
    for (int it = 0; it < SITER; ++it) {
        const int u  = it * 512 + tid;
        const bool vu = u < NPAIR2;
        const int uu = vu ? u : 0;
        const int c4 = uu / NH, hidx = uu - c4 * NH;
        const int hy = hidx / HC, hx = hidx - hy * HC;
        const int h = h0 - 1 + hy, w = hx - 1;
        const bool ok = vu && (unsigned)h < (unsigned)H_ && (unsigned)w < (unsigned)W_;
        st.xrel[it] = ok ? (4 * c4 * HW_ + h * W_ + w) : 0;
        st.okm |= (ok ? 1u : 0u) << it;
    }

    f32x4 acc[4][7] = {};
    short8 afr[2][4];
    float bs[SITER][4];

    // prologue: stage chunks 0 and 1 into buf0/buf1; A step 0 -> afr[0]
    load_a(afr[0], st, 0);
    issue_b(st, 0, bs);
    write_b(st, 0 * BSZ, bs);
    issue_b(st, 32, bs);
    write_b(st, 1 * BSZ, bs);
    asm volatile("s_waitcnt lgkmcnt(0)" ::: "memory");
    __builtin_amdgcn_s_barrier();

    do_chunk<0, true,  false>(0, st, afr, acc, bs);
    do_chunk<1, true,  true >(1, st, afr, acc, bs);
    do_chunk<2, true,  false>(2, st, afr, acc, bs);
    do_chunk<3, true,  true >(3, st, afr, acc, bs);
    do_chunk<0, true,  false>(4, st, afr, acc, bs);
    do_chunk<1, true,  true >(5, st, afr, acc, bs);
    do_chunk<2, false, false>(6, st, afr, acc, bs);
    do_chunk<3, false, false>(7, st, afr, acc, bs);

    // ---- alpha from P2/P3 partials (deterministic block-local reduce) ----
    __syncthreads();                       // all LDS B-reads done; reuse lds as scratch
    float* sred = (float*)lds;
    float s2 = wsc[WS_P2 + tid] + wsc[WS_P2 + 512 + tid];
    float s3 = wsc[WS_P3 + tid] + wsc[WS_P3 + 512 + tid];
    if (tid < NQB - 1024) {
        s2 += wsc[WS_P2 + 1024 + tid];
        s3 += wsc[WS_P3 + 1024 + tid];
    }
    #pragma unroll
    for (int o = 32; o > 0; o >>= 1) { s2 += __shfl_down(s2, o, 64); s3 += __shfl_down(s3, o, 64); }
    if (lane == 0) { sred[wid] = s2; sred[8 + wid] = s3; }
    __syncthreads();
    float msum = 0.f, mcnt = 0.f;
    #pragma unroll
    for (int i = 0; i < 8; ++i) { msum += sred[i]; mcnt += sred[8 + i]; }
    const float alpha = mcnt > 0.f ? msum / fmaxf(mcnt, 1.f) : 1.0f;

    // ---- epilogue: alpha scale, contiguous-x stores (R4 order) ----
    #pragma unroll
    for (int mf = 0; mf < 4; ++mf) {
        const int k = wm * 64 + mf * 16 + lg * 4;
        #pragma unroll
        for (int nf = 0; nf < 7; ++nf) {
            const int pos = wn * 112 + nf * 16 + lr;
            const int y = pos / 56, xx = pos - y * 56;
            float* po = out + ((size_t)n * K_ + k) * HW_ + (h0 + y) * W_ + xx;
            #pragma unroll
            for (int j = 0; j < 4; ++j)
                po[(size_t)j * HW_] = alpha * acc[mf][nf][j];
        }
    }
}

// ---------------- fallback direct conv (tiny ws) ----------------
constexpr int W4_ = W_ / 4;
constexpr int SP_ = H_ * W4_;
__global__ __launch_bounds__(256) void conv_tern_otf(const float* __restrict__ x,
                                                     const float* __restrict__ wt,
                                                     const float* __restrict__ wsc,
                                                     float* __restrict__ out) {
    const int kg = blockIdx.x, n = blockIdx.y, k0 = kg * 4;
    const float thr = 0.75f * wsc[0] / (float)NW_;
    const float cnt = wsc[2];
    const float alpha = cnt > 0.f ? wsc[1] / fmaxf(cnt, 1.f) : 1.0f;
    for (int j = 0; j < 4; ++j) {
        const int sp = (int)threadIdx.x + j * 256;
        if (sp >= SP_) break;
        const int h = sp / W4_, w0 = (sp % W4_) * 4;
        float acc[4][4];
        #pragma unroll
        for (int kt = 0; kt < 4; ++kt)
            #pragma unroll
            for (int jj = 0; jj < 4; ++jj) acc[kt][jj] = 0.f;
        for (int c = 0; c < C_; ++c) {
            const float* xp = x + (((size_t)n * C_ + c) * H_) * W_;
            float xr[3][6];
            #pragma unroll
            for (int r = 0; r < 3; ++r) {
                const int hh = h + r - 1;
                const float* rowp = xp + hh * W_;
                if ((unsigned)hh < (unsigned)H_) {
                    const float4 mid = *(const float4*)(rowp + w0);
                    xr[r][1] = mid.x; xr[r][2] = mid.y; xr[r][3] = mid.z; xr[r][4] = mid.w;
                    xr[r][0] = (w0 > 0)      ? rowp[w0 - 1] : 0.f;
                    xr[r][5] = (w0 + 4 < W_) ? rowp[w0 + 4] : 0.f;
                } else {
                    #pragma unroll
                    for (int q = 0; q < 6; ++q) xr[r][q] = 0.f;
                }
            }
            #pragma unroll
            for (int kt = 0; kt < 4; ++kt) {
                const float* wp = wt + ((size_t)(k0 + kt) * C_ + c) * 9;
                #pragma unroll
                for (int r = 0; r < 3; ++r)
                    #pragma unroll
                    for (int s = 0; s < 3; ++s) {
                        float wv = wp[r * 3 + s];
                        wv = wv > thr ? alpha : (wv < -thr ? -alpha : 0.f);
                        #pragma unroll
                        for (int jj = 0; jj < 4; ++jj)
                            acc[kt][jj] = fmaf(wv, xr[r][jj + s], acc[kt][jj]);
                    }
            }
        }
        #pragma unroll
        for (int kt = 0; kt < 4; ++kt) {
            float4 o;
            o.x = acc[kt][0]; o.y = acc[kt][1]; o.z = acc[kt][2]; o.w = acc[kt][3];
            *(float4*)(out + ((((size_t)n * K_ + (k0 + kt)) * H_ + h) * W_ + w0)) = o;
        }
    }
}

extern "C" void kernel_launch(void* const* d_in, const int* in_sizes, int n_in,
                              void* d_out, int out_size, void* d_ws, size_t ws_size,
                              hipStream_t stream) {
    const float* x = (const float*)d_in[0];
    const float* w = (const float*)d_in[1];
    float* out = (float*)d_out;
    float* ws  = (float*)d_ws;
    unsigned short* wq = (unsigned short*)((char*)d_ws + WS_WQ);

    k_abs_partial<<<256, 256, 0, stream>>>(w, ws);

    if (ws_size >= WS_NEEDED) {
        k_quant<<<NQB, 512, 0, stream>>>(w, ws, wq);
        hipFuncSetAttribute((const void*)conv_mfma,
                            hipFuncAttributeMaxDynamicSharedMemorySize, LDSB);
        dim3 grid(NB, N_);
        conv_mfma<<<grid, 512, LDSB, stream>>>(x, wq, ws, out);
    } else {
        k_fb_total<<<1, 256, 0, stream>>>(ws);
        k_fb_masked<<<256, 256, 0, stream>>>(w, ws);
        k_final_masked<<<1, 256, 0, stream>>>(ws);
        dim3 grid(64, N_);
        conv_tern_otf<<<grid, 256, 0, stream>>>(x, w, ws, out);
    }
}

// Round 11
// 128.273 us; speedup vs baseline: 1.1224x; 1.1224x over previous
//
#include <hip/hip_runtime.h>
#include <hip/hip_bf16.h>

typedef short short8 __attribute__((ext_vector_type(8)));
typedef float f32x4 __attribute__((ext_vector_type(4)));

constexpr int N_  = 32;
constexpr int C_  = 256;
constexpr int K_  = 256;
constexpr int H_  = 56;
constexpr int W_  = 56;
constexpr int HW_ = H_ * W_;             // 3136
constexpr int NW_ = K_ * C_ * 9;         // 589824

constexpr int TH   = 4;                  // output rows per band (128B-aligned writes)
constexpr int NB   = 14;                 // bands
constexpr int HR   = 6, HC = 58;         // halo rows/cols
constexpr int NH   = HR * HC;            // 348 halo positions
constexpr int BROW = 80;                 // B LDS row stride (32c bf16 = 64B + 16 pad)
constexpr int BSZ  = NH * BROW;          // 27840 per buffer
constexpr int NPAIR2 = 8 * NH;           // 2784 (c-quad, hidx) staging elems
constexpr int SITER  = 6;                // ceil(2784/512)
constexpr int ASTEP  = 16384;            // one step-tile: 256k x 32c bf16

constexpr int NQB   = 1152;              // quant blocks (589824 / 512, exact)
constexpr int WS_P1 = 4;                 // 256 abs partials
constexpr int WS_P2 = 300;               // 1152 masked-sum partials
constexpr int WS_P3 = 1500;              // 1152 masked-cnt partials
constexpr size_t WS_WQ = 16384;
constexpr size_t WS_NEEDED = WS_WQ + (size_t)NW_ * 2;

__device__ __forceinline__ unsigned f2bf(float f) {  // RNE fp32->bf16 bits
    unsigned u = __builtin_bit_cast(unsigned, f);
    return (u + 0x7FFFu + ((u >> 16) & 1u)) >> 16;
}

// ---------------- reductions (deterministic, no atomics) ----------------
__global__ void k_abs_partial(const float* __restrict__ w, float* __restrict__ ws) {
    __shared__ float sm[4];
    float s = 0.f;
    for (int i = blockIdx.x * 256 + threadIdx.x; i < NW_; i += 256 * 256)
        s += fabsf(w[i]);
    #pragma unroll
    for (int o = 32; o > 0; o >>= 1) s += __shfl_down(s, o, 64);
    const int wid = threadIdx.x >> 6, lane = threadIdx.x & 63;
    if (lane == 0) sm[wid] = s;
    __syncthreads();
    if (threadIdx.x == 0) {
        float r = 0.f;
        for (int i = 0; i < 4; ++i) r += sm[i];
        ws[WS_P1 + blockIdx.x] = r;
    }
}

__device__ __forceinline__ float reduce256_all(const float* __restrict__ p, float* sm) {
    float v = threadIdx.x < 256 ? p[threadIdx.x] : 0.f;
    #pragma unroll
    for (int o = 32; o > 0; o >>= 1) v += __shfl_down(v, o, 64);
    const int wid = threadIdx.x >> 6, lane = threadIdx.x & 63;
    __syncthreads();
    if (lane == 0) sm[wid] = v;
    __syncthreads();
    float total = 0.f;
    #pragma unroll
    for (int i = 0; i < 8; ++i) total += sm[i];
    return total;
}

// quantize signs to bf16 {+1,-1,0} in [step=(chi*9+rs)][k][c5] layout AND write
// per-block masked partials (sum,cnt) -> P2/P3. Grid = 1152 x 512 (exact cover).
__global__ __launch_bounds__(512) void k_quant(const float* __restrict__ w,
                                               float* __restrict__ ws,
                                               unsigned short* __restrict__ wq) {
    __shared__ float sm[8];
    const float total = reduce256_all(ws + WS_P1, sm);
    const float thr = 0.75f * total / (float)NW_;
    const int i = blockIdx.x * 512 + threadIdx.x;
    const float v = w[i];
    const unsigned short q = v > thr ? (unsigned short)0x3F80
                                     : (v < -thr ? (unsigned short)0xBF80 : (unsigned short)0);
    const int k   = i / 2304;
    const int rem = i - k * 2304;
    const int c   = rem / 9;
    const int rs  = rem - c * 9;
    const int chi = c >> 5, c5 = c & 31;
    wq[(size_t)(chi * 9 + rs) * 8192 + (k << 5) + c5] = q;
    // masked partials for alpha
    const float a = fabsf(v);
    float s = a > thr ? a : 0.f;
    float cn = a > thr ? 1.f : 0.f;
    #pragma unroll
    for (int o = 32; o > 0; o >>= 1) { s += __shfl_down(s, o, 64); cn += __shfl_down(cn, o, 64); }
    __shared__ float sm2[16];
    const int wid = threadIdx.x >> 6, lane = threadIdx.x & 63;
    __syncthreads();
    if (lane == 0) { sm2[wid] = s; sm2[8 + wid] = cn; }
    __syncthreads();
    if (threadIdx.x == 0) {
        float S = 0.f, C2 = 0.f;
        for (int j = 0; j < 8; ++j) { S += sm2[j]; C2 += sm2[8 + j]; }
        ws[WS_P2 + blockIdx.x] = S;
        ws[WS_P3 + blockIdx.x] = C2;
    }
}

// ---------------- fallback-path helper kernels (tiny ws only) ----------------
__global__ void k_fb_total(float* __restrict__ ws) {
    __shared__ float sm[4];
    float v = ws[WS_P1 + threadIdx.x];
    #pragma unroll
    for (int o = 32; o > 0; o >>= 1) v += __shfl_down(v, o, 64);
    const int wid = threadIdx.x >> 6, lane = threadIdx.x & 63;
    if (lane == 0) sm[wid] = v;
    __syncthreads();
    if (threadIdx.x == 0) {
        float r = 0.f;
        for (int i = 0; i < 4; ++i) r += sm[i];
        ws[0] = r;
    }
}

__global__ void k_fb_masked(const float* __restrict__ w, float* __restrict__ ws) {
    const float thr = 0.75f * ws[0] / (float)NW_;
    float s = 0.f, c = 0.f;
    for (int i = blockIdx.x * 256 + threadIdx.x; i < NW_; i += 256 * 256) {
        float a = fabsf(w[i]);
        if (a > thr) { s += a; c += 1.f; }
    }
    #pragma unroll
    for (int o = 32; o > 0; o >>= 1) { s += __shfl_down(s, o, 64); c += __shfl_down(c, o, 64); }
    __shared__ float sm[8];
    const int wid = threadIdx.x >> 6, lane = threadIdx.x & 63;
    if (lane == 0) { sm[wid] = s; sm[4 + wid] = c; }
    __syncthreads();
    if (threadIdx.x == 0) {
        float S = 0.f, C2 = 0.f;
        for (int i = 0; i < 4; ++i) { S += sm[i]; C2 += sm[i + 4]; }
        ws[WS_P2 + blockIdx.x] = S;
        ws[WS_P3 + blockIdx.x] = C2;
    }
}

__global__ void k_final_masked(float* __restrict__ ws) {
    __shared__ float sm[8];
    float s = ws[WS_P2 + threadIdx.x];
    float c = ws[WS_P3 + threadIdx.x];
    #pragma unroll
    for (int o = 32; o > 0; o >>= 1) { s += __shfl_down(s, o, 64); c += __shfl_down(c, o, 64); }
    const int wid = threadIdx.x >> 6, lane = threadIdx.x & 63;
    if (lane == 0) { sm[wid] = s; sm[4 + wid] = c; }
    __syncthreads();
    if (threadIdx.x == 0) {
        float S = 0.f, C2 = 0.f;
        for (int i = 0; i < 4; ++i) { S += sm[i]; C2 += sm[i + 4]; }
        ws[1] = S; ws[2] = C2;
    }
}

// ---------------- MFMA conv: exact R4 champion structure ----------------
// Block: 256k x 224pos (4 rows x 56 cols), 8 waves = 4(k) x 2(pos).
// Wave: 64k x 112pos (4x7 frags, 28 MFMA / 4 A-glb / 7 B-lds reads per 32-ch step).
// A: direct global->reg from L2-resident wq, depth-1 parity pipeline (register waits).
// B: x halo (6x58) per chunk, double-buffered LDS; issue rs==6, write rs==8,
//    one barrier per chunk. Alpha computed in epilogue from k_quant partials.
constexpr int RSO_[9] = {
    (0*HC+0)*BROW, (0*HC+1)*BROW, (0*HC+2)*BROW,
    (1*HC+0)*BROW, (1*HC+1)*BROW, (1*HC+2)*BROW,
    (2*HC+0)*BROW, (2*HC+1)*BROW, (2*HC+2)*BROW };

struct ConvState {
    const float* xn;
    const char*  wqc;
    char*        ldsp;
    size_t       aoff;      // per-lane byte offset within a step tile
    int          h0, tid;
    int          bB[7];     // per-lane B frag byte offsets within a buffer
};

__device__ __forceinline__ void load_a(short8 (&d)[4], const ConvState& st, int step) {
    const char* ap = st.wqc + (size_t)step * ASTEP + st.aoff;
    d[0] = *(const short8*)(ap);
    d[1] = *(const short8*)(ap + 1024);
    d[2] = *(const short8*)(ap + 2048);
    d[3] = *(const short8*)(ap + 3072);
}

// issue next chunk's x quads into registers (pack deferred to write_b)
__device__ __forceinline__ void issue_b(const ConvState& st, int c0,
                                        float (&bs)[SITER][4], unsigned& bmask) {
    bmask = 0;
    #pragma unroll
    for (int it = 0; it < SITER; ++it) {
        const int u  = it * 512 + st.tid;
        const bool vu = u < NPAIR2;
        const int uu = vu ? u : 0;
        const int c4 = uu / NH, hidx = uu - c4 * NH;
        const int hy = hidx / HC, hx = hidx - hy * HC;
        const int h  = st.h0 - 1 + hy, w = hx - 1;
        const bool ok = vu && (unsigned)h < (unsigned)H_ && (unsigned)w < (unsigned)W_;
        const int off = ok ? ((c0 + 4 * c4) * HW_ + h * W_ + w) : 0;
        const float* p = st.xn + off;
        bs[it][0] = p[0];
        bs[it][1] = p[HW_];
        bs[it][2] = p[2 * HW_];
        bs[it][3] = p[3 * HW_];
        bmask |= (ok ? 1u : 0u) << it;
    }
}

__device__ __forceinline__ void write_b(const ConvState& st, int base,
                                        const float (&bs)[SITER][4], unsigned bmask) {
    #pragma unroll
    for (int it = 0; it < SITER; ++it) {
        const int u = it * 512 + st.tid;
        if (u < NPAIR2) {
            const int c4 = u / NH, hidx = u - c4 * NH;
            const bool ok = (bmask >> it) & 1u;
            const float f0 = ok ? bs[it][0] : 0.f;
            const float f1 = ok ? bs[it][1] : 0.f;
            const float f2 = ok ? bs[it][2] : 0.f;
            const float f3 = ok ? bs[it][3] : 0.f;
            uint2 v;
            v.x = f2bf(f0) | (f2bf(f1) << 16);
            v.y = f2bf(f2) | (f2bf(f3) << 16);
            *(uint2*)(st.ldsp + base + hidx * BROW + c4 * 8) = v;
        }
    }
}

template <int PAR, bool LASTCH>
__device__ __forceinline__ void do_chunk(int chi, const ConvState& st,
                                         short8 (&afr)[2][4], f32x4 (&acc)[4][7],
                                         float (&bs)[SITER][4], unsigned& bmask) {
    const int rdbase = PAR * BSZ;
    #pragma unroll
    for (int rs = 0; rs < 9; ++rs) {
        const int cur = (PAR + rs) & 1, nxt = cur ^ 1;
        const int step = chi * 9 + rs;
        if (!(LASTCH && rs == 8))
            load_a(afr[nxt], st, step + 1);   // next step's A into the other reg set

        short8 bfr[7];
        #pragma unroll
        for (int nf = 0; nf < 7; ++nf)
            bfr[nf] = *(const short8*)(st.ldsp + rdbase + st.bB[nf] + RSO_[rs]);

        __builtin_amdgcn_s_setprio(1);
        #pragma unroll
        for (int nf = 0; nf < 7; ++nf)
            #pragma unroll
            for (int mf = 0; mf < 4; ++mf)
                acc[mf][nf] = __builtin_amdgcn_mfma_f32_16x16x32_bf16(
                    afr[cur][mf], bfr[nf], acc[mf][nf], 0, 0, 0);
        __builtin_amdgcn_s_setprio(0);

        if (rs == 6 && !LASTCH)
            issue_b(st, (chi + 1) * 32, bs, bmask);   // next chunk's x, 2 steps of hiding
        if (rs == 8 && !LASTCH) {
            write_b(st, (PAR ^ 1) * BSZ, bs, bmask);
            asm volatile("s_waitcnt lgkmcnt(0)" ::: "memory");
            __builtin_amdgcn_s_barrier();             // only sync point: B buffer handoff
        }
    }
}

__global__ __launch_bounds__(512, 2) void conv_mfma(const float* __restrict__ x,
                                                    const unsigned short* __restrict__ wq,
                                                    const float* __restrict__ wsc,
                                                    float* __restrict__ out) {
    __shared__ char lds[2 * BSZ];
    const int tid = threadIdx.x, lane = tid & 63, wid = tid >> 6;
    const int wm = wid & 3, wn = wid >> 2, lr = lane & 15, lg = lane >> 4;
    const int band = blockIdx.x, n = blockIdx.y;

    ConvState st;
    st.xn   = x + (size_t)n * C_ * HW_;
    st.wqc  = (const char*)wq;
    st.ldsp = lds;
    st.aoff = (size_t)(wm * 64 + lr) * 64 + lg * 16;
    st.h0   = band * TH;
    st.tid  = tid;
    #pragma unroll
    for (int nf = 0; nf < 7; ++nf) {
        const int pos = wn * 112 + nf * 16 + lr;
        const int y = pos / 56, xx = pos - y * 56;
        st.bB[nf] = (y * HC + xx) * BROW + lg * 16;
    }

    f32x4 acc[4][7] = {};
    short8 afr[2][4];
    float bs[SITER][4];
    unsigned bmask;

    // prologue: B chunk 0 -> buf0; A step 0 -> afr[0]
    issue_b(st, 0, bs, bmask);
    load_a(afr[0], st, 0);
    write_b(st, 0, bs, bmask);
    asm volatile("s_waitcnt lgkmcnt(0)" ::: "memory");
    __builtin_amdgcn_s_barrier();

    for (int cc = 0; cc < 3; ++cc) {
        do_chunk<0, false>(2 * cc,     st, afr, acc, bs, bmask);
        do_chunk<1, false>(2 * cc + 1, st, afr, acc, bs, bmask);
    }
    do_chunk<0, false>(6, st, afr, acc, bs, bmask);
    do_chunk<1, true >(7, st, afr, acc, bs, bmask);

    // ---- alpha from P2/P3 partials (deterministic block-local reduce) ----
    __syncthreads();                       // all LDS B-reads done; reuse lds as scratch
    float* sred = (float*)lds;
    float s2 = wsc[WS_P2 + tid] + wsc[WS_P2 + 512 + tid];
    float s3 = wsc[WS_P3 + tid] + wsc[WS_P3 + 512 + tid];
    if (tid < NQB - 1024) {
        s2 += wsc[WS_P2 + 1024 + tid];
        s3 += wsc[WS_P3 + 1024 + tid];
    }
    #pragma unroll
    for (int o = 32; o > 0; o >>= 1) { s2 += __shfl_down(s2, o, 64); s3 += __shfl_down(s3, o, 64); }
    if (lane == 0) { sred[wid] = s2; sred[8 + wid] = s3; }
    __syncthreads();
    float msum = 0.f, mcnt = 0.f;
    #pragma unroll
    for (int i = 0; i < 8; ++i) { msum += sred[i]; mcnt += sred[8 + i]; }
    const float alpha = mcnt > 0.f ? msum / fmaxf(mcnt, 1.f) : 1.0f;

    // ---- epilogue: alpha scale, contiguous-x stores (R4 order) ----
    #pragma unroll
    for (int mf = 0; mf < 4; ++mf) {
        const int k = wm * 64 + mf * 16 + lg * 4;
        #pragma unroll
        for (int nf = 0; nf < 7; ++nf) {
            const int pos = wn * 112 + nf * 16 + lr;
            const int y = pos / 56, xx = pos - y * 56;
            float* po = out + ((size_t)n * K_ + k) * HW_ + (st.h0 + y) * W_ + xx;
            #pragma unroll
            for (int j = 0; j < 4; ++j)
                po[(size_t)j * HW_] = alpha * acc[mf][nf][j];
        }
    }
}

// ---------------- fallback direct conv (tiny ws) ----------------
constexpr int W4_ = W_ / 4;
constexpr int SP_ = H_ * W4_;
__global__ __launch_bounds__(256) void conv_tern_otf(const float* __restrict__ x,
                                                     const float* __restrict__ wt,
                                                     const float* __restrict__ wsc,
                                                     float* __restrict__ out) {
    const int kg = blockIdx.x, n = blockIdx.y, k0 = kg * 4;
    const float thr = 0.75f * wsc[0] / (float)NW_;
    const float cnt = wsc[2];
    const float alpha = cnt > 0.f ? wsc[1] / fmaxf(cnt, 1.f) : 1.0f;
    for (int j = 0; j < 4; ++j) {
        const int sp = (int)threadIdx.x + j * 256;
        if (sp >= SP_) break;
        const int h = sp / W4_, w0 = (sp % W4_) * 4;
        float acc[4][4];
        #pragma unroll
        for (int kt = 0; kt < 4; ++kt)
            #pragma unroll
            for (int jj = 0; jj < 4; ++jj) acc[kt][jj] = 0.f;
        for (int c = 0; c < C_; ++c) {
            const float* xp = x + (((size_t)n * C_ + c) * H_) * W_;
            float xr[3][6];
            #pragma unroll
            for (int r = 0; r < 3; ++r) {
                const int hh = h + r - 1;
                const float* rowp = xp + hh * W_;
                if ((unsigned)hh < (unsigned)H_) {
                    const float4 mid = *(const float4*)(rowp + w0);
                    xr[r][1] = mid.x; xr[r][2] = mid.y; xr[r][3] = mid.z; xr[r][4] = mid.w;
                    xr[r][0] = (w0 > 0)      ? rowp[w0 - 1] : 0.f;
                    xr[r][5] = (w0 + 4 < W_) ? rowp[w0 + 4] : 0.f;
                } else {
                    #pragma unroll
                    for (int q = 0; q < 6; ++q) xr[r][q] = 0.f;
                }
            }
            #pragma unroll
            for (int kt = 0; kt < 4; ++kt) {
                const float* wp = wt + ((size_t)(k0 + kt) * C_ + c) * 9;
                #pragma unroll
                for (int r = 0; r < 3; ++r)
                    #pragma unroll
                    for (int s = 0; s < 3; ++s) {
                        float wv = wp[r * 3 + s];
                        wv = wv > thr ? alpha : (wv < -thr ? -alpha : 0.f);
                        #pragma unroll
                        for (int jj = 0; jj < 4; ++jj)
                            acc[kt][jj] = fmaf(wv, xr[r][jj + s], acc[kt][jj]);
                    }
            }
        }
        #pragma unroll
        for (int kt = 0; kt < 4; ++kt) {
            float4 o;
            o.x = acc[kt][0]; o.y = acc[kt][1]; o.z = acc[kt][2]; o.w = acc[kt][3];
            *(float4*)(out + ((((size_t)n * K_ + (k0 + kt)) * H_ + h) * W_ + w0)) = o;
        }
    }
}

extern "C" void kernel_launch(void* const* d_in, const int* in_sizes, int n_in,
                              void* d_out, int out_size, void* d_ws, size_t ws_size,
                              hipStream_t stream) {
    const float* x = (const float*)d_in[0];
    const float* w = (const float*)d_in[1];
    float* out = (float*)d_out;
    float* ws  = (float*)d_ws;
    unsigned short* wq = (unsigned short*)((char*)d_ws + WS_WQ);

    k_abs_partial<<<256, 256, 0, stream>>>(w, ws);

    if (ws_size >= WS_NEEDED) {
        k_quant<<<NQB, 512, 0, stream>>>(w, ws, wq);
        dim3 grid(NB, N_);
        conv_mfma<<<grid, 512, 0, stream>>>(x, wq, ws, out);
    } else {
        k_fb_total<<<1, 256, 0, stream>>>(ws);
        k_fb_masked<<<256, 256, 0, stream>>>(w, ws);
        k_final_masked<<<1, 256, 0, stream>>>(ws);
        dim3 grid(64, N_);
        conv_tern_otf<<<grid, 256, 0, stream>>>(x, w, ws, out);
    }
}